// Round 4
// baseline (2802.155 us; speedup 1.0000x reference)
//
#include <hip/hip_runtime.h>

#define NN 50000
#define EE 400000
#define FF 128
#define NRBF 20
#define MAXDEG 64
#define NT 16
#define KT 32
#define PI_OVER_CUT 0.6283185307179586f   // pi / 5.0

// Swizzled weight tile: 128 rows x 32 cols, element (g,k) at [g*32 + ((k+g)&31)].
// Read by lane g0 at fixed k: bank (k+g0)%32 -> exactly 2-way across 64 lanes = free.
// Measured 0 SQ_LDS_BANK_CONFLICT in R3.
#define WREAD(wb, g, k) wb[((g) << 5) + (((k) + (g)) & 31)]

__device__ __forceinline__ void stage_w(const float* __restrict__ W, int ldw,
                                        int j0, float* __restrict__ wb, int t) {
    #pragma unroll
    for (int p = 0; p < 4; ++p) {
        int r = t + 256 * p;          // 0..1023
        int g = r >> 3;               // 0..127
        int c4 = (r & 7) * 4;         // 0,4,...,28
        float4 w = *(const float4*)&W[(size_t)g * ldw + j0 + c4];
        int base = g << 5;
        wb[base + ((c4 + 0 + g) & 31)] = w.x;
        wb[base + ((c4 + 1 + g) & 31)] = w.y;
        wb[base + ((c4 + 2 + g) & 31)] = w.z;
        wb[base + ((c4 + 3 + g) & 31)] = w.w;
    }
}

// ---------------------------------------------------------------------------
__global__ __launch_bounds__(256) void k_zero(int* __restrict__ counts) {
    int i = blockIdx.x * 256 + threadIdx.x;
    if (i < NN) counts[i] = 0;
}

__global__ __launch_bounds__(256) void k_bucket(const int* __restrict__ dst,
                                                int* __restrict__ counts,
                                                int* __restrict__ slots) {
    int e = blockIdx.x * 256 + threadIdx.x;
    if (e < EE) {
        int n = dst[e];
        int slot = atomicAdd(&counts[n], 1);
        if (slot < MAXDEG) slots[n * MAXDEG + slot] = e;
    }
}

// ---------------------------------------------------------------------------
// K1: phi_s/phi_v + s0 out. x-side via wave-uniform global loads (emb rows);
// weights via swizzled LDS tiles. LDS 24 KB, VGPR<=128 -> 4+ blocks/CU.
__global__ __launch_bounds__(256, 4) void k_node_phi(
    const float* __restrict__ emb, const int* __restrict__ z,
    const float* __restrict__ Wp1, const float* __restrict__ bp1,
    const float* __restrict__ Wp2, const float* __restrict__ bp2,
    float* __restrict__ phi_s, float* __restrict__ phi_v,
    float* __restrict__ s_io)
{
    __shared__ float h1_t[NT][FF];   // 8 KB
    __shared__ float wbuf[4096];     // 16 KB
    const int t  = threadIdx.x;
    const int g0 = t & 63;
    const int hu = __builtin_amdgcn_readfirstlane(t >> 6);   // wave-uniform
    const int n0 = blockIdx.x * NT;

    // wave-uniform emb row pointers for this wave's 4 nodes
    const float* __restrict__ xrow[4];
    #pragma unroll
    for (int i = 0; i < 4; ++i) {
        int zi = z[n0 + hu + 4 * i];   // uniform load
        xrow[i] = emb + (size_t)zi * FF;
    }

    // ---- phase 1: h1 = silu(Wp1 @ s0 + bp1), K=128 ----
    float acc[2][4];
    #pragma unroll
    for (int a = 0; a < 2; a++)
        #pragma unroll
        for (int i = 0; i < 4; i++) acc[a][i] = 0.f;

    for (int jt = 0; jt < 4; ++jt) {
        const int j0 = jt * KT;
        __syncthreads();
        stage_w(Wp1, FF, j0, wbuf, t);
        __syncthreads();
        for (int kk = 0; kk < KT; kk += 4) {
            float wa[4], wc[4];
            #pragma unroll
            for (int q = 0; q < 4; ++q) {
                wa[q] = WREAD(wbuf, g0, kk + q);
                wc[q] = WREAD(wbuf, g0 + 64, kk + q);
            }
            #pragma unroll
            for (int i = 0; i < 4; ++i) {
                float4 x4 = *(const float4*)&xrow[i][j0 + kk];   // uniform
                acc[0][i] += wa[0]*x4.x + wa[1]*x4.y + wa[2]*x4.z + wa[3]*x4.w;
                acc[1][i] += wc[0]*x4.x + wc[1]*x4.y + wc[2]*x4.z + wc[3]*x4.w;
            }
        }
    }
    __syncthreads();
    {
        float b1a = bp1[g0], b1b = bp1[g0 + 64];
        #pragma unroll
        for (int i = 0; i < 4; i++) {
            int n = hu + 4 * i;
            float xa = acc[0][i] + b1a;
            float xb = acc[1][i] + b1b;
            h1_t[n][g0]      = xa / (1.f + __expf(-xa));
            h1_t[n][g0 + 64] = xb / (1.f + __expf(-xb));
        }
    }

    // ---- phase 2: phi_s (Wp2 rows 0:128), phi_v (rows 256:384), K=128 ----
    float A[2][2][4];
    #pragma unroll
    for (int gR = 0; gR < 2; gR++)
        #pragma unroll
        for (int a = 0; a < 2; a++)
            #pragma unroll
            for (int i = 0; i < 4; i++) A[gR][a][i] = 0.f;

    #pragma unroll
    for (int gR = 0; gR < 2; ++gR) {
        const float* Wsrc = Wp2 + (size_t)(gR == 0 ? 0 : 256) * FF;
        for (int jt = 0; jt < 4; ++jt) {
            const int j0 = jt * KT;
            __syncthreads();
            stage_w(Wsrc, FF, j0, wbuf, t);
            __syncthreads();
            for (int kk = 0; kk < KT; kk += 4) {
                float wa[4], wc[4];
                #pragma unroll
                for (int q = 0; q < 4; ++q) {
                    wa[q] = WREAD(wbuf, g0, kk + q);
                    wc[q] = WREAD(wbuf, g0 + 64, kk + q);
                }
                #pragma unroll
                for (int i = 0; i < 4; ++i) {
                    int n = hu + 4 * i;
                    float4 x4 = *(const float4*)&h1_t[n][j0 + kk];  // broadcast
                    A[gR][0][i] += wa[0]*x4.x + wa[1]*x4.y + wa[2]*x4.z + wa[3]*x4.w;
                    A[gR][1][i] += wc[0]*x4.x + wc[1]*x4.y + wc[2]*x4.z + wc[3]*x4.w;
                }
            }
        }
    }
    {
        float bsa = bp2[g0], bsb = bp2[g0 + 64];
        float bva = bp2[256 + g0], bvb = bp2[256 + g0 + 64];
        #pragma unroll
        for (int i = 0; i < 4; i++) {
            int n = hu + 4 * i;
            size_t gi = (size_t)(n0 + n) * FF;
            phi_s[gi + g0]      = A[0][0][i] + bsa;
            phi_s[gi + g0 + 64] = A[0][1][i] + bsb;
            phi_v[gi + g0]      = A[1][0][i] + bva;
            phi_v[gi + g0 + 64] = A[1][1][i] + bvb;
            s_io[gi + g0]       = xrow[i][g0];
            s_io[gi + g0 + 64]  = xrow[i][g0 + 64];
        }
    }
}

// ---------------------------------------------------------------------------
// K2: per-destination-node message accumulation (unchanged).
__global__ __launch_bounds__(128) void k_edge(
    const float* __restrict__ pos,
    const float* __restrict__ Ww, const float* __restrict__ bw,
    const int* __restrict__ src,
    const int* __restrict__ counts, const int* __restrict__ slots,
    const float* __restrict__ phi_s, const float* __restrict__ phi_v,
    float* __restrict__ s_io, float* __restrict__ v_io)
{
    const int n = blockIdx.x;
    const int f = threadIdx.x;
    const int lane = threadIdx.x & 63;

    float ww_s[NRBF], ww_v[NRBF];
    #pragma unroll
    for (int k = 0; k < NRBF; k++) {
        ww_s[k] = Ww[f * NRBF + k];
        ww_v[k] = Ww[(256 + f) * NRBF + k];
    }
    const float bws = bw[f], bwv = bw[256 + f];
    const float px = pos[3 * n], py = pos[3 * n + 1], pz = pos[3 * n + 2];

    float acc_s = 0.f, av0 = 0.f, av1 = 0.f, av2 = 0.f;
    int deg = counts[n];
    deg = deg > MAXDEG ? MAXDEG : deg;

    for (int i = 0; i < deg; i++) {
        int e  = slots[n * MAXDEG + i];
        int sI = src[e];
        float rx = px - pos[3 * sI];
        float ry = py - pos[3 * sI + 1];
        float rz = pz - pos[3 * sI + 2];
        float d = sqrtf(rx * rx + ry * ry + rz * rz);
        d = fmaxf(d, 1e-9f);
        float dinv = 1.f / d;
        int kk = lane < NRBF ? lane : (NRBF - 1);
        float rbf_l = __sinf((float)(kk + 1) * PI_OVER_CUT * d) * dinv;
        int rbf_i = __float_as_int(rbf_l);
        float wfs = bws, wfv = bwv;
        #pragma unroll
        for (int k = 0; k < NRBF; k++) {
            float rk = __int_as_float(__builtin_amdgcn_readlane(rbf_i, k));
            wfs = fmaf(ww_s[k], rk, wfs);
            wfv = fmaf(ww_v[k], rk, wfv);
        }
        float sp_s = phi_s[(size_t)sI * FF + f] * wfs;
        float sp_v = phi_v[(size_t)sI * FF + f] * wfv;
        acc_s += sp_s;
        av0 = fmaf(sp_v, rx * dinv, av0);
        av1 = fmaf(sp_v, ry * dinv, av1);
        av2 = fmaf(sp_v, rz * dinv, av2);
    }
    size_t gi = (size_t)n * FF + f;
    s_io[gi] += acc_s;
    v_io[gi * 3 + 0] = av0;
    v_io[gi * 3 + 1] = av1;
    v_io[gi * 3 + 2] = av2;
}

// ---------------------------------------------------------------------------
// K3: fused update. x-side from wave-uniform global loads (v rows, s rows),
// Vn/h1 via one 8 KB LDS buffer; weights via swizzled LDS tiles.
// LDS 24 KB, VGPR<=128 -> 4 blocks/CU (16 waves).
__global__ __launch_bounds__(256, 4) void k_update(
    const float* __restrict__ Wu, const float* __restrict__ bu,
    const float* __restrict__ Wv, const float* __restrict__ bv,
    const float* __restrict__ Wu1, const float* __restrict__ bu1,
    const float* __restrict__ Wu2, const float* __restrict__ bu2,
    float* __restrict__ s_io, float* __restrict__ v_io)
{
    __shared__ float xn_t[NT][FF];   // 8 KB: Vn, then h1
    __shared__ float wbuf[4096];     // 16 KB swizzled weight tile
    const int t  = threadIdx.x;
    const int g0 = t & 63;
    const int hu = __builtin_amdgcn_readfirstlane(t >> 6);   // wave-uniform
    const int n0 = blockIdx.x * NT;

    const float* __restrict__ vrow[4];
    const float* __restrict__ srow[4];
    #pragma unroll
    for (int i = 0; i < 4; ++i) {
        int n = n0 + hu + 4 * i;
        vrow[i] = v_io + (size_t)n * (FF * 3);
        srow[i] = s_io + (size_t)n * FF;
    }

    // ---- phase 1: U = v@Wu^T, V = v@Wv^T (3 comps), K=128 ----
    float U[2][4][3], V[2][4][3];
    #pragma unroll
    for (int a = 0; a < 2; a++)
        #pragma unroll
        for (int i = 0; i < 4; i++)
            #pragma unroll
            for (int c = 0; c < 3; c++) { U[a][i][c] = 0.f; V[a][i][c] = 0.f; }

    for (int jt = 0; jt < 4; ++jt) {
        const int j0 = jt * KT;
        // Wu pass
        __syncthreads();
        stage_w(Wu, FF, j0, wbuf, t);
        __syncthreads();
        for (int kk = 0; kk < KT; kk += 4) {
            float wa[4], wc[4];
            #pragma unroll
            for (int q = 0; q < 4; ++q) {
                wa[q] = WREAD(wbuf, g0, kk + q);
                wc[q] = WREAD(wbuf, g0 + 64, kk + q);
            }
            #pragma unroll
            for (int i = 0; i < 4; ++i) {
                const float4* xp = (const float4*)(vrow[i] + (size_t)(j0 + kk) * 3);
                float4 xa = xp[0], xb = xp[1], xc = xp[2];   // uniform, 48B
                float xs0[3] = { xa.x, xa.y, xa.z };
                float xs1[3] = { xa.w, xb.x, xb.y };
                float xs2[3] = { xb.z, xb.w, xc.x };
                float xs3[3] = { xc.y, xc.z, xc.w };
                #pragma unroll
                for (int c = 0; c < 3; ++c) {
                    U[0][i][c] += wa[0]*xs0[c] + wa[1]*xs1[c] + wa[2]*xs2[c] + wa[3]*xs3[c];
                    U[1][i][c] += wc[0]*xs0[c] + wc[1]*xs1[c] + wc[2]*xs2[c] + wc[3]*xs3[c];
                }
            }
        }
        // Wv pass (re-reads x: uniform loads are L1-hot)
        __syncthreads();
        stage_w(Wv, FF, j0, wbuf, t);
        __syncthreads();
        for (int kk = 0; kk < KT; kk += 4) {
            float wa[4], wc[4];
            #pragma unroll
            for (int q = 0; q < 4; ++q) {
                wa[q] = WREAD(wbuf, g0, kk + q);
                wc[q] = WREAD(wbuf, g0 + 64, kk + q);
            }
            #pragma unroll
            for (int i = 0; i < 4; ++i) {
                const float4* xp = (const float4*)(vrow[i] + (size_t)(j0 + kk) * 3);
                float4 xa = xp[0], xb = xp[1], xc = xp[2];
                float xs0[3] = { xa.x, xa.y, xa.z };
                float xs1[3] = { xa.w, xb.x, xb.y };
                float xs2[3] = { xb.z, xb.w, xc.x };
                float xs3[3] = { xc.y, xc.z, xc.w };
                #pragma unroll
                for (int c = 0; c < 3; ++c) {
                    V[0][i][c] += wa[0]*xs0[c] + wa[1]*xs1[c] + wa[2]*xs2[c] + wa[3]*xs3[c];
                    V[1][i][c] += wc[0]*xs0[c] + wc[1]*xs1[c] + wc[2]*xs2[c] + wc[3]*xs3[c];
                }
            }
        }
    }

    float uv[2][4];
    {
        float buv[2] = { bu[g0], bu[g0 + 64] };
        float bvv[2] = { bv[g0], bv[g0 + 64] };
        #pragma unroll
        for (int a = 0; a < 2; a++) {
            #pragma unroll
            for (int i = 0; i < 4; i++) {
                const int n = hu + 4 * i;
                #pragma unroll
                for (int c = 0; c < 3; c++) {
                    U[a][i][c] += buv[a];
                    V[a][i][c] += bvv[a];
                }
                float vx = V[a][i][0], vy = V[a][i][1], vz = V[a][i][2];
                xn_t[n][g0 + 64 * a] = sqrtf(vx * vx + vy * vy + vz * vz);  // Vn
                uv[a][i] = U[a][i][0] * vx + U[a][i][1] * vy + U[a][i][2] * vz;
            }
        }
    }
    // Vn writes ordered by the next pre-stage barrier

    // ---- phase 2: h1 = silu(Wu1 @ [s;Vn] + bu1), K=256 ----
    float hacc[2][4];
    #pragma unroll
    for (int a = 0; a < 2; a++)
        #pragma unroll
        for (int i = 0; i < 4; i++) hacc[a][i] = 0.f;

    for (int jt = 0; jt < 8; ++jt) {
        const int j0 = jt * KT;
        __syncthreads();
        stage_w(Wu1, 256, j0, wbuf, t);
        __syncthreads();
        const int jl = (jt & 3) * KT;
        for (int kk = 0; kk < KT; kk += 4) {
            float wa[4], wc[4];
            #pragma unroll
            for (int q = 0; q < 4; ++q) {
                wa[q] = WREAD(wbuf, g0, kk + q);
                wc[q] = WREAD(wbuf, g0 + 64, kk + q);
            }
            #pragma unroll
            for (int i = 0; i < 4; ++i) {
                int n = hu + 4 * i;
                float4 x4 = (jt < 4)
                    ? *(const float4*)&srow[i][jl + kk]       // uniform global
                    : *(const float4*)&xn_t[n][jl + kk];      // LDS broadcast
                hacc[0][i] += wa[0]*x4.x + wa[1]*x4.y + wa[2]*x4.z + wa[3]*x4.w;
                hacc[1][i] += wc[0]*x4.x + wc[1]*x4.y + wc[2]*x4.z + wc[3]*x4.w;
            }
        }
    }
    __syncthreads();   // all Vn reads complete before overwrite
    {
        float b1a = bu1[g0], b1b = bu1[g0 + 64];
        #pragma unroll
        for (int i = 0; i < 4; i++) {
            int n = hu + 4 * i;
            float xa = hacc[0][i] + b1a;
            float xb = hacc[1][i] + b1b;
            xn_t[n][g0]      = xa / (1.f + __expf(-xa));   // h1
            xn_t[n][g0 + 64] = xb / (1.f + __expf(-xb));
        }
    }

    // ---- phase 3: a = Wu2 @ h1 (3 row groups), K=128 ----
    float A[3][2][4];
    #pragma unroll
    for (int r = 0; r < 3; r++)
        #pragma unroll
        for (int a = 0; a < 2; a++)
            #pragma unroll
            for (int i = 0; i < 4; i++) A[r][a][i] = 0.f;

    for (int rg = 0; rg < 3; ++rg) {
        const float* Wsrc = Wu2 + (size_t)rg * 128 * FF;
        for (int jt = 0; jt < 4; ++jt) {
            const int j0 = jt * KT;
            __syncthreads();
            stage_w(Wsrc, FF, j0, wbuf, t);
            __syncthreads();
            for (int kk = 0; kk < KT; kk += 4) {
                float wa[4], wc[4];
                #pragma unroll
                for (int q = 0; q < 4; ++q) {
                    wa[q] = WREAD(wbuf, g0, kk + q);
                    wc[q] = WREAD(wbuf, g0 + 64, kk + q);
                }
                #pragma unroll
                for (int i = 0; i < 4; ++i) {
                    int n = hu + 4 * i;
                    float4 x4 = *(const float4*)&xn_t[n][j0 + kk];
                    A[rg][0][i] += wa[0]*x4.x + wa[1]*x4.y + wa[2]*x4.z + wa[3]*x4.w;
                    A[rg][1][i] += wc[0]*x4.x + wc[1]*x4.y + wc[2]*x4.z + wc[3]*x4.w;
                }
            }
        }
    }

    {
        float ba1[2] = { bu2[g0],       bu2[g0 + 64]  };
        float ba2[2] = { bu2[128 + g0], bu2[192 + g0] };
        float ba3[2] = { bu2[256 + g0], bu2[320 + g0] };
        #pragma unroll
        for (int a = 0; a < 2; a++) {
            const int g = g0 + 64 * a;
            #pragma unroll
            for (int i = 0; i < 4; i++) {
                const size_t gi = (size_t)(n0 + hu + 4 * i) * FF + g;
                float aa1 = A[0][a][i] + ba1[a];
                float aa2 = A[1][a][i] + ba2[a];
                float aa3 = A[2][a][i] + ba3[a];
                s_io[gi] = srow[i][g] + aa2 + uv[a][i] * aa3;
                v_io[gi * 3 + 0] = vrow[i][g * 3 + 0] + U[a][i][0] * aa1;
                v_io[gi * 3 + 1] = vrow[i][g * 3 + 1] + U[a][i][1] * aa1;
                v_io[gi * 3 + 2] = vrow[i][g * 3 + 2] + U[a][i][2] * aa1;
            }
        }
    }
}

// ---------------------------------------------------------------------------
extern "C" void kernel_launch(void* const* d_in, const int* in_sizes, int n_in,
                              void* d_out, int out_size, void* d_ws, size_t ws_size,
                              hipStream_t stream)
{
    const float* pos = (const float*)d_in[0];
    const float* emb = (const float*)d_in[1];
    const float* Wp1 = (const float*)d_in[2];
    const float* bp1 = (const float*)d_in[3];
    const float* Wp2 = (const float*)d_in[4];
    const float* bp2 = (const float*)d_in[5];
    const float* Ww  = (const float*)d_in[6];
    const float* bw  = (const float*)d_in[7];
    const float* Wu  = (const float*)d_in[8];
    const float* bu  = (const float*)d_in[9];
    const float* Wv  = (const float*)d_in[10];
    const float* bv  = (const float*)d_in[11];
    const float* Wu1 = (const float*)d_in[12];
    const float* bu1 = (const float*)d_in[13];
    const float* Wu2 = (const float*)d_in[14];
    const float* bu2 = (const float*)d_in[15];
    const int* z   = (const int*)d_in[16];
    const int* src = (const int*)d_in[17];
    const int* dst = (const int*)d_in[18];

    float* s_io = (float*)d_out;
    float* v_io = (float*)d_out + (size_t)NN * FF;

    char* ws = (char*)d_ws;
    float* phi_s = (float*)ws;
    float* phi_v = phi_s + (size_t)NN * FF;
    int*   counts = (int*)(phi_v + (size_t)NN * FF);
    int*   slots  = counts + NN;

    k_zero  <<<(NN + 255) / 256, 256, 0, stream>>>(counts);
    k_bucket<<<(EE + 255) / 256, 256, 0, stream>>>(dst, counts, slots);
    k_node_phi<<<NN / NT, 256, 0, stream>>>(emb, z, Wp1, bp1, Wp2, bp2,
                                            phi_s, phi_v, s_io);
    k_edge<<<NN, 128, 0, stream>>>(pos, Ww, bw, src, counts, slots,
                                   phi_s, phi_v, s_io, v_io);
    k_update<<<NN / NT, 256, 0, stream>>>(Wu, bu, Wv, bv, Wu1, bu1, Wu2, bu2,
                                          s_io, v_io);
}